// Round 2
// baseline (186.122 us; speedup 1.0000x reference)
//
#include <hip/hip_runtime.h>

typedef __attribute__((ext_vector_type(4))) float f32x4;
typedef __attribute__((ext_vector_type(8))) short s16x8;

#define NSKIN 128
#define NG    8000
#define NRPT  8000
#define M_TILE 64
#define N_TILE 256
#define KK     32
#define KCH    2000
#define NKC    4
#define NMB    2
#define NRB    32
#define TPB    512

__device__ __forceinline__ float sin_rev(float u){ float r; asm("v_sin_f32 %0, %1" : "=v"(r) : "v"(u)); return r; }
__device__ __forceinline__ float cos_rev(float u){ float r; asm("v_cos_f32 %0, %1" : "=v"(r) : "v"(u)); return r; }

__device__ __forceinline__ unsigned short f2bf(float f){
    unsigned int x = __float_as_uint(f);
    x += 0x7FFFu + ((x >> 16) & 1u);   // RNE
    return (unsigned short)(x >> 16);
}

__device__ __forceinline__ s16x8 bneg(s16x8 v){
    int4 u = *(int4*)&v;
    u.x ^= 0x80008000; u.y ^= 0x80008000; u.z ^= 0x80008000; u.w ^= 0x80008000;
    return *(s16x8*)&u;
}

__global__ __launch_bounds__(TPB) void bloch_mfma_kernel(
    const float* __restrict__ Amat, const float* __restrict__ kgrid,
    const float* __restrict__ cgr,  const float* __restrict__ cgi,
    const float* __restrict__ rpts, float* __restrict__ out, int out_size)
{
    __shared__ float fracS[N_TILE][4];
    __shared__ float rkS[N_TILE][4];
    __shared__ float invAS[9];
    __shared__ float scaleS;
    __shared__ unsigned short Ar[M_TILE][KK+8];
    __shared__ unsigned short Ai[M_TILE][KK+8];
    __shared__ unsigned short Bc[N_TILE][KK+8];
    __shared__ unsigned short Bs[N_TILE][KK+8];

    const int tid = threadIdx.x;
    const int b   = blockIdx.x;
    const int kc  = b & 3;
    const int rb  = (b >> 2) & 31;
    const int mb  = b >> 7;
    const int m_base  = mb * M_TILE;
    const int r_base  = rb * N_TILE;
    const int k_begin = kc * KCH;
    const int k_end   = k_begin + KCH;

    if (tid == 0) {
        float a00=Amat[0],a01=Amat[1],a02=Amat[2];
        float a10=Amat[3],a11=Amat[4],a12=Amat[5];
        float a20=Amat[6],a21=Amat[7],a22=Amat[8];
        float c00 =  (a11*a22 - a12*a21);
        float c01 = -(a10*a22 - a12*a20);
        float c02 =  (a10*a21 - a11*a20);
        float det = a00*c00 + a01*c01 + a02*c02;
        float id  = 1.0f/det;
        invAS[0] =  c00*id;
        invAS[1] = -(a01*a22 - a02*a21)*id;
        invAS[2] =  (a01*a12 - a02*a11)*id;
        invAS[3] =  c01*id;
        invAS[4] =  (a00*a22 - a02*a20)*id;
        invAS[5] = -(a00*a12 - a02*a10)*id;
        invAS[6] =  c02*id;
        invAS[7] = -(a00*a21 - a01*a20)*id;
        invAS[8] =  (a00*a11 - a01*a10)*id;
        scaleS   = rsqrtf(fabsf(det));
    }
    __syncthreads();

    if (tid < N_TILE) {
        int rg = r_base + tid; if (rg > NRPT-1) rg = NRPT-1;
        float r0 = rpts[rg*3+0], r1 = rpts[rg*3+1], r2 = rpts[rg*3+2];
        fracS[tid][0] = r0*invAS[0] + r1*invAS[3] + r2*invAS[6];
        fracS[tid][1] = r0*invAS[1] + r1*invAS[4] + r2*invAS[7];
        fracS[tid][2] = r0*invAS[2] + r1*invAS[5] + r2*invAS[8];
        #pragma unroll
        for (int kk = 0; kk < 4; ++kk)
            rkS[tid][kk] = r0*kgrid[kk*3+0] + r1*kgrid[kk*3+1] + r2*kgrid[kk*3+2];
    }
    __syncthreads();

    f32x4 accRe[2][4], accIm[2][4];
    #pragma unroll
    for (int mi = 0; mi < 2; ++mi)
        #pragma unroll
        for (int ni = 0; ni < 4; ++ni) {
            accRe[mi][ni] = (f32x4){0.f,0.f,0.f,0.f};
            accIm[mi][ni] = (f32x4){0.f,0.f,0.f,0.f};
        }

    const int lane = tid & 63;
    const int wid  = tid >> 6;
    const int wm   = wid >> 2;      // 0..1
    const int wn   = wid & 3;       // 0..3
    const int m0   = wm * 32;
    const int n0   = wn * 64;
    const int frow = lane & 15;
    const int k0   = (lane >> 4) * 8;

    const int sa   = tid >> 3;      // A-staging: skin row 0..63
    const int sega = tid & 7;       // float4 segment 0..7
    const int rB   = tid >> 1;      // B-staging: r 0..255
    const int halfB= tid & 1;       // k half 0..1

    const float f0 = fracS[rB][0], f1 = fracS[rB][1], f2 = fracS[rB][2];

    for (int kb = k_begin; kb < k_end; kb += KK) {
        // ---- stage A (cg fp32 -> bf16), zero-pad beyond chunk end ----
        {
            int kg = kb + sega*4;
            float4 vr = make_float4(0.f,0.f,0.f,0.f);
            float4 vi = make_float4(0.f,0.f,0.f,0.f);
            if (kg < k_end) {
                vr = *(const float4*)&cgr[(size_t)(m_base+sa)*NG + kg];
                vi = *(const float4*)&cgi[(size_t)(m_base+sa)*NG + kg];
            }
            ushort4 pr, pi;
            pr.x = f2bf(vr.x); pr.y = f2bf(vr.y); pr.z = f2bf(vr.z); pr.w = f2bf(vr.w);
            pi.x = f2bf(vi.x); pi.y = f2bf(vi.y); pi.z = f2bf(vi.z); pi.w = f2bf(vi.w);
            *(ushort4*)&Ar[sa][sega*4] = pr;
            *(ushort4*)&Ai[sa][sega*4] = pi;
        }
        // ---- stage B: phases cos/sin(2*pi*m.frac) as bf16 ----
        {
            #pragma unroll
            for (int jj = 0; jj < 16; jj += 4) {
                ushort4 pc, ps;
                #pragma unroll
                for (int e = 0; e < 4; ++e) {
                    int g  = kb + halfB*16 + jj + e;
                    int i1 = g / 400;
                    int g2 = g - i1*400;
                    int i2 = g2 / 20;
                    int i3 = g2 - i2*20;
                    float m1 = (float)(i1 - (i1 >= 10 ? 20 : 0));
                    float m2 = (float)(i2 - (i2 >= 10 ? 20 : 0));
                    float m3 = (float)(i3 - (i3 >= 10 ? 20 : 0));
                    float ang = m1*f0 + m2*f1 + m3*f2;     // revolutions
                    float u = ang - floorf(ang);
                    unsigned short cb = f2bf(cos_rev(u));
                    unsigned short sb = f2bf(sin_rev(u));
                    ((unsigned short*)&pc)[e] = cb;
                    ((unsigned short*)&ps)[e] = sb;
                }
                *(ushort4*)&Bc[rB][halfB*16+jj] = pc;
                *(ushort4*)&Bs[rB][halfB*16+jj] = ps;
            }
        }
        __syncthreads();

        // ---- fragments + MFMA ----
        s16x8 arf[2], aif[2], ainf[2];
        #pragma unroll
        for (int mi = 0; mi < 2; ++mi) {
            arf[mi] = *(const s16x8*)&Ar[m0 + mi*16 + frow][k0];
            aif[mi] = *(const s16x8*)&Ai[m0 + mi*16 + frow][k0];
            ainf[mi] = bneg(aif[mi]);
        }
        s16x8 bcf[4], bsf[4];
        #pragma unroll
        for (int ni = 0; ni < 4; ++ni) {
            int col = n0 + ni*16 + frow;
            bcf[ni] = *(const s16x8*)&Bc[col][k0];
            bsf[ni] = *(const s16x8*)&Bs[col][k0];
        }
        #pragma unroll
        for (int mi = 0; mi < 2; ++mi)
            #pragma unroll
            for (int ni = 0; ni < 4; ++ni) {
                // Re += Ar*cos + (-Ai)*sin ; Im += Ar*sin + Ai*cos
                accRe[mi][ni] = __builtin_amdgcn_mfma_f32_16x16x32_bf16(arf[mi],  bcf[ni], accRe[mi][ni], 0, 0, 0);
                accRe[mi][ni] = __builtin_amdgcn_mfma_f32_16x16x32_bf16(ainf[mi], bsf[ni], accRe[mi][ni], 0, 0, 0);
                accIm[mi][ni] = __builtin_amdgcn_mfma_f32_16x16x32_bf16(arf[mi],  bsf[ni], accIm[mi][ni], 0, 0, 0);
                accIm[mi][ni] = __builtin_amdgcn_mfma_f32_16x16x32_bf16(aif[mi],  bcf[ni], accIm[mi][ni], 0, 0, 0);
            }
        __syncthreads();
    }

    // ---- epilogue: apply exp(i k.r)/sqrt(vol), atomic-accumulate ----
    // out_size == NSKIN*NRPT      -> real part only (complex64 ref cast to f32)
    // out_size == 2*NSKIN*NRPT    -> interleaved (re,im) float pairs
    const bool write_imag = (out_size >= 2*NSKIN*NRPT);
    const float scale  = scaleS;
    const float inv2pi = 0.15915494309189535f;
    #pragma unroll
    for (int mi = 0; mi < 2; ++mi) {
        const int kidx = ((m_base + m0 + mi*16) >> 4) & 3;
        #pragma unroll
        for (int ni = 0; ni < 4; ++ni) {
            int colr = n0 + ni*16 + frow;
            int rg = r_base + colr;
            if (rg < NRPT) {
                float ang = rkS[colr][kidx] * inv2pi;
                float u = ang - floorf(ang);
                float ck = cos_rev(u), sk = sin_rev(u);
                #pragma unroll
                for (int v = 0; v < 4; ++v) {
                    int sg = m_base + m0 + mi*16 + (lane >> 4)*4 + v;
                    float re = accRe[mi][ni][v];
                    float im = accIm[mi][ni][v];
                    float orr = (re*ck - im*sk) * scale;
                    size_t lin = (size_t)sg * NRPT + rg;
                    if (write_imag) {
                        float oi = (re*sk + im*ck) * scale;
                        size_t idx = lin * 2;
                        if (idx + 1 < (size_t)out_size) {
                            atomicAdd(&out[idx],   orr);
                            atomicAdd(&out[idx+1], oi);
                        }
                    } else {
                        if (lin < (size_t)out_size)
                            atomicAdd(&out[lin], orr);
                    }
                }
            }
        }
    }
}

extern "C" void kernel_launch(void* const* d_in, const int* in_sizes, int n_in,
                              void* d_out, int out_size, void* d_ws, size_t ws_size,
                              hipStream_t stream) {
    const float* Amat  = (const float*)d_in[0];
    const float* kgrid = (const float*)d_in[1];
    const float* cgr   = (const float*)d_in[2];
    const float* cgi   = (const float*)d_in[3];
    const float* rpts  = (const float*)d_in[4];
    float* out = (float*)d_out;

    hipMemsetAsync(d_out, 0, (size_t)out_size * sizeof(float), stream);

    dim3 grid(NMB * NRB * NKC);   // 2*32*4 = 256 blocks
    bloch_mfma_kernel<<<grid, TPB, 0, stream>>>(Amat, kgrid, cgr, cgi, rpts, out, out_size);
}

// Round 3
// 117.455 us; speedup vs baseline: 1.5846x; 1.5846x over previous
//
#include <hip/hip_runtime.h>

typedef __attribute__((ext_vector_type(4))) float f32x4;
typedef __attribute__((ext_vector_type(8))) short s16x8;

#define NSKIN 128
#define NG    8000
#define NRPT  8000
#define MT    128
#define NT    128
#define KK    32
#define KCH   2000
#define NKC   4
#define NRB   64
#define TPB   512
#define PIT   40      // ushorts per LDS tile row (80B) -> 5 granules, 2-way free

__device__ __forceinline__ float sin_rev(float u){ float r; asm("v_sin_f32 %0, %1" : "=v"(r) : "v"(u)); return r; }
__device__ __forceinline__ float cos_rev(float u){ float r; asm("v_cos_f32 %0, %1" : "=v"(r) : "v"(u)); return r; }
__device__ __forceinline__ unsigned int cvt_pk(float lo, float hi){
    unsigned int r; asm("v_cvt_pk_bf16_f32 %0, %1, %2" : "=v"(r) : "v"(lo), "v"(hi)); return r;
}
__device__ __forceinline__ s16x8 bneg(s16x8 v){
    int4 u = *(int4*)&v;
    u.x ^= 0x80008000; u.y ^= 0x80008000; u.z ^= 0x80008000; u.w ^= 0x80008000;
    return *(s16x8*)&u;
}

__global__ __launch_bounds__(TPB) void bloch_mfma2(
    const float* __restrict__ Amat, const float* __restrict__ kgrid,
    const float* __restrict__ cgr,  const float* __restrict__ cgi,
    const float* __restrict__ rpts, float* __restrict__ out, int out_size)
{
    __shared__ float fracS[NT][4];
    __shared__ float rkS[NT][4];
    __shared__ unsigned int T3[NT][20];          // packed bf16 (cos lo, sin hi)
    __shared__ unsigned short Ar[MT][PIT], Ai[MT][PIT];
    __shared__ unsigned short Bc[NT][PIT], Bs[NT][PIT];
    __shared__ float invAS[9];
    __shared__ float scaleS;

    const int tid = threadIdx.x;
    const int bid = blockIdx.x;
    // XCD-aware: same-kc blocks share a 2MB cg k-slice -> same XCD pair's L2
    const int x   = bid & 7;
    const int kc  = x >> 1;                       // 0..3
    const int rb  = ((bid >> 3) << 1) | (x & 1);  // 0..63
    const int r_base  = rb * NT;
    const int k_begin = kc * KCH;
    const int k_end   = k_begin + KCH;

    if (tid == 0) {
        float a00=Amat[0],a01=Amat[1],a02=Amat[2];
        float a10=Amat[3],a11=Amat[4],a12=Amat[5];
        float a20=Amat[6],a21=Amat[7],a22=Amat[8];
        float c00 =  (a11*a22 - a12*a21);
        float c01 = -(a10*a22 - a12*a20);
        float c02 =  (a10*a21 - a11*a20);
        float det = a00*c00 + a01*c01 + a02*c02;
        float id  = 1.0f/det;
        invAS[0] =  c00*id;
        invAS[1] = -(a01*a22 - a02*a21)*id;
        invAS[2] =  (a01*a12 - a02*a11)*id;
        invAS[3] =  c01*id;
        invAS[4] =  (a00*a22 - a02*a20)*id;
        invAS[5] = -(a00*a12 - a02*a10)*id;
        invAS[6] =  c02*id;
        invAS[7] = -(a00*a21 - a01*a20)*id;
        invAS[8] =  (a00*a11 - a01*a10)*id;
        scaleS   = rsqrtf(fabsf(det));
    }
    __syncthreads();

    if (tid < NT) {
        int rg = r_base + tid; if (rg > NRPT-1) rg = NRPT-1;
        float r0 = rpts[rg*3+0], r1 = rpts[rg*3+1], r2 = rpts[rg*3+2];
        fracS[tid][0] = r0*invAS[0] + r1*invAS[3] + r2*invAS[6];
        fracS[tid][1] = r0*invAS[1] + r1*invAS[4] + r2*invAS[7];
        fracS[tid][2] = r0*invAS[2] + r1*invAS[5] + r2*invAS[8];
        #pragma unroll
        for (int kk = 0; kk < 4; ++kk)
            rkS[tid][kk] = r0*kgrid[kk*3+0] + r1*kgrid[kk*3+1] + r2*kgrid[kk*3+2];
    }
    __syncthreads();

    // build T3[r][i3] = e^{2*pi*i * m3 * f2}, bf16-packed
    for (int e = tid; e < NT*20; e += TPB) {
        int r  = (e * 3277) >> 16;      // e/20
        int i3 = e - r*20;
        float m3 = (float)(i3 - (i3 >= 10 ? 20 : 0));
        float ang = m3 * fracS[r][2];
        float u = ang - floorf(ang);
        T3[r][i3] = cvt_pk(cos_rev(u), sin_rev(u));
    }
    __syncthreads();

    f32x4 accRe[4][2], accIm[4][2];
    #pragma unroll
    for (int mi = 0; mi < 4; ++mi)
        #pragma unroll
        for (int ni = 0; ni < 2; ++ni) {
            accRe[mi][ni] = (f32x4){0.f,0.f,0.f,0.f};
            accIm[mi][ni] = (f32x4){0.f,0.f,0.f,0.f};
        }

    const int lane = tid & 63;
    const int wid  = tid >> 6;
    const int wm   = wid >> 2;      // 0..1  (M half)
    const int wn   = wid & 3;       // 0..3  (N quarter)
    const int frow = lane & 15;
    const int k0   = (lane >> 4) * 8;

    const int sa      = tid >> 2;   // A-staging row 0..127
    const int seg     = tid & 3;    // k segment of 8
    const int rB      = tid >> 2;   // B-staging r-row 0..127
    const int quarter = tid & 3;    // g segment of 8

    const float f0r = fracS[rB][0], f1r = fracS[rB][1];

    for (int kb = k_begin; kb < k_end; kb += KK) {
        // ---- stage A: cg fp32 -> bf16 (zero-pad past chunk end) ----
        {
            int kg = kb + seg*8;
            uint4 pr, pi;
            if (kg < k_end) {
                const float4 v0r = *(const float4*)&cgr[(size_t)sa*NG + kg];
                const float4 v1r = *(const float4*)&cgr[(size_t)sa*NG + kg + 4];
                const float4 v0i = *(const float4*)&cgi[(size_t)sa*NG + kg];
                const float4 v1i = *(const float4*)&cgi[(size_t)sa*NG + kg + 4];
                pr.x = cvt_pk(v0r.x, v0r.y); pr.y = cvt_pk(v0r.z, v0r.w);
                pr.z = cvt_pk(v1r.x, v1r.y); pr.w = cvt_pk(v1r.z, v1r.w);
                pi.x = cvt_pk(v0i.x, v0i.y); pi.y = cvt_pk(v0i.z, v0i.w);
                pi.z = cvt_pk(v1i.x, v1i.y); pi.w = cvt_pk(v1i.z, v1i.w);
            } else {
                pr = make_uint4(0,0,0,0); pi = make_uint4(0,0,0,0);
            }
            *(uint4*)&Ar[sa][seg*8] = pr;
            *(uint4*)&Ai[sa][seg*8] = pi;
        }
        // ---- stage B: phase = P12(i1,i2) * T3(i3), no per-element sincos ----
        {
            int g0  = kb + quarter*8;
            int i12 = (g0 * 3277) >> 16;            // g0/20
            int i3_0 = g0 - i12*20;
            int i1a = (i12 * 3277) >> 16; int i2a = i12 - i1a*20;
            int i12b = i12 + 1;
            int i1b = (i12b * 3277) >> 16; int i2b = i12b - i1b*20;
            float m1a = (float)(i1a - (i1a >= 10 ? 20 : 0));
            float m2a = (float)(i2a - (i2a >= 10 ? 20 : 0));
            float m1b = (float)(i1b - (i1b >= 10 ? 20 : 0));
            float m2b = (float)(i2b - (i2b >= 10 ? 20 : 0));
            float aa = m1a*f0r + m2a*f1r; aa -= floorf(aa);
            float ab = m1b*f0r + m2b*f1r; ab -= floorf(ab);
            float ca = cos_rev(aa), sa2 = sin_rev(aa);
            float cb = cos_rev(ab), sb2 = sin_rev(ab);
            float bcv[8], bsv[8];
            #pragma unroll
            for (int j = 0; j < 8; ++j) {
                int t = i3_0 + j;
                bool wr = (t >= 20);
                int i3 = wr ? t - 20 : t;
                unsigned int pk = T3[rB][i3];
                float t3c = __uint_as_float(pk << 16);
                float t3s = __uint_as_float(pk & 0xFFFF0000u);
                float pc = wr ? cb : ca;
                float ps = wr ? sb2 : sa2;
                bcv[j] = pc*t3c - ps*t3s;
                bsv[j] = pc*t3s + ps*t3c;
            }
            uint4 wc, wsn;
            wc.x  = cvt_pk(bcv[0], bcv[1]); wc.y  = cvt_pk(bcv[2], bcv[3]);
            wc.z  = cvt_pk(bcv[4], bcv[5]); wc.w  = cvt_pk(bcv[6], bcv[7]);
            wsn.x = cvt_pk(bsv[0], bsv[1]); wsn.y = cvt_pk(bsv[2], bsv[3]);
            wsn.z = cvt_pk(bsv[4], bsv[5]); wsn.w = cvt_pk(bsv[6], bsv[7]);
            *(uint4*)&Bc[rB][quarter*8] = wc;
            *(uint4*)&Bs[rB][quarter*8] = wsn;
        }
        __syncthreads();

        // ---- fragments + MFMA: wave tile 64(m) x 32(n) ----
        s16x8 bcf[2], bsf[2];
        #pragma unroll
        for (int ni = 0; ni < 2; ++ni) {
            int col = wn*32 + ni*16 + frow;
            bcf[ni] = *(const s16x8*)&Bc[col][k0];
            bsf[ni] = *(const s16x8*)&Bs[col][k0];
        }
        #pragma unroll
        for (int mi = 0; mi < 4; ++mi) {
            int row = wm*64 + mi*16 + frow;
            s16x8 arf = *(const s16x8*)&Ar[row][k0];
            s16x8 aif = *(const s16x8*)&Ai[row][k0];
            s16x8 ainf = bneg(aif);
            #pragma unroll
            for (int ni = 0; ni < 2; ++ni) {
                accRe[mi][ni] = __builtin_amdgcn_mfma_f32_16x16x32_bf16(arf,  bcf[ni], accRe[mi][ni], 0, 0, 0);
                accRe[mi][ni] = __builtin_amdgcn_mfma_f32_16x16x32_bf16(ainf, bsf[ni], accRe[mi][ni], 0, 0, 0);
                accIm[mi][ni] = __builtin_amdgcn_mfma_f32_16x16x32_bf16(arf,  bsf[ni], accIm[mi][ni], 0, 0, 0);
                accIm[mi][ni] = __builtin_amdgcn_mfma_f32_16x16x32_bf16(aif,  bcf[ni], accIm[mi][ni], 0, 0, 0);
            }
        }
        __syncthreads();
    }

    // ---- epilogue: rotate by exp(i k.r), scale, atomic-accumulate ----
    const bool write_imag = (out_size >= 2*NSKIN*NRPT);
    const float scale  = scaleS;
    const float inv2pi = 0.15915494309189535f;
    #pragma unroll
    for (int mi = 0; mi < 4; ++mi) {
        const int m0 = wm*64 + mi*16;
        const int kidx = (m0 >> 4) & 3;
        #pragma unroll
        for (int ni = 0; ni < 2; ++ni) {
            int col = wn*32 + ni*16 + frow;
            int rg = r_base + col;
            if (rg < NRPT) {
                float ang = rkS[col][kidx] * inv2pi;
                float u = ang - floorf(ang);
                float ck = cos_rev(u), sk = sin_rev(u);
                #pragma unroll
                for (int v = 0; v < 4; ++v) {
                    int sg = m0 + (lane >> 4)*4 + v;
                    float re = accRe[mi][ni][v];
                    float im = accIm[mi][ni][v];
                    float orr = (re*ck - im*sk) * scale;
                    size_t lin = (size_t)sg * NRPT + rg;
                    if (write_imag) {
                        float oi = (re*sk + im*ck) * scale;
                        size_t idx = lin * 2;
                        if (idx + 1 < (size_t)out_size) {
                            atomicAdd(&out[idx],   orr);
                            atomicAdd(&out[idx+1], oi);
                        }
                    } else {
                        if (lin < (size_t)out_size)
                            atomicAdd(&out[lin], orr);
                    }
                }
            }
        }
    }
}

extern "C" void kernel_launch(void* const* d_in, const int* in_sizes, int n_in,
                              void* d_out, int out_size, void* d_ws, size_t ws_size,
                              hipStream_t stream) {
    const float* Amat  = (const float*)d_in[0];
    const float* kgrid = (const float*)d_in[1];
    const float* cgr   = (const float*)d_in[2];
    const float* cgi   = (const float*)d_in[3];
    const float* rpts  = (const float*)d_in[4];
    float* out = (float*)d_out;

    hipMemsetAsync(d_out, 0, (size_t)out_size * sizeof(float), stream);

    dim3 grid(NRB * NKC);   // 64 rb x 4 kc = 256 blocks (1/CU)
    bloch_mfma2<<<grid, TPB, 0, stream>>>(Amat, kgrid, cgr, cgi, rpts, out, out_size);
}

// Round 4
// 109.723 us; speedup vs baseline: 1.6963x; 1.0705x over previous
//
#include <hip/hip_runtime.h>

typedef __attribute__((ext_vector_type(4))) float f32x4;
typedef __attribute__((ext_vector_type(8))) short s16x8;

#define NSKIN 128
#define NG    8000
#define NRPT  8000
#define MT    128
#define NT    128
#define KK    32
#define KCH   1000
#define NKC   8
#define NRB   64
#define TPB   512
#define PIT   40      // ushorts per LDS tile row (80B)

__device__ __forceinline__ float sin_rev(float u){ float r; asm("v_sin_f32 %0, %1" : "=v"(r) : "v"(u)); return r; }
__device__ __forceinline__ float cos_rev(float u){ float r; asm("v_cos_f32 %0, %1" : "=v"(r) : "v"(u)); return r; }
__device__ __forceinline__ unsigned int cvt_pk(float lo, float hi){
    unsigned int r; asm("v_cvt_pk_bf16_f32 %0, %1, %2" : "=v"(r) : "v"(lo), "v"(hi)); return r;
}
__device__ __forceinline__ s16x8 bneg(s16x8 v){
    int4 u = *(int4*)&v;
    u.x ^= 0x80008000; u.y ^= 0x80008000; u.z ^= 0x80008000; u.w ^= 0x80008000;
    return *(s16x8*)&u;
}

__global__ __launch_bounds__(TPB, 4) void bloch_mfma3(
    const float* __restrict__ Amat, const float* __restrict__ kgrid,
    const float* __restrict__ cgr,  const float* __restrict__ cgi,
    const float* __restrict__ rpts, float* __restrict__ out, int out_size)
{
    __shared__ float fracS[NT][4];
    __shared__ float rkS[NT][4];
    __shared__ unsigned int T3[NT][20];          // packed bf16 (cos lo, sin hi)
    __shared__ unsigned short Ar[MT][PIT], Ai[MT][PIT];
    __shared__ unsigned short Bc[NT][PIT], Bs[NT][PIT];
    __shared__ float invAS[9];
    __shared__ float scaleS;

    const int tid = threadIdx.x;
    const int bid = blockIdx.x;
    // kc = bid&7: all blocks sharing a cg k-slice land on one XCD (L2 locality);
    // co-resident partner (bid+256) has same kc -> A loads L2-hit.
    const int kc  = bid & 7;
    const int rb  = bid >> 3;                     // 0..63
    const int r_base  = rb * NT;
    const int k_begin = kc * KCH;
    const int k_end   = k_begin + KCH;

    if (tid == 0) {
        float a00=Amat[0],a01=Amat[1],a02=Amat[2];
        float a10=Amat[3],a11=Amat[4],a12=Amat[5];
        float a20=Amat[6],a21=Amat[7],a22=Amat[8];
        float c00 =  (a11*a22 - a12*a21);
        float c01 = -(a10*a22 - a12*a20);
        float c02 =  (a10*a21 - a11*a20);
        float det = a00*c00 + a01*c01 + a02*c02;
        float id  = 1.0f/det;
        invAS[0] =  c00*id;
        invAS[1] = -(a01*a22 - a02*a21)*id;
        invAS[2] =  (a01*a12 - a02*a11)*id;
        invAS[3] =  c01*id;
        invAS[4] =  (a00*a22 - a02*a20)*id;
        invAS[5] = -(a00*a12 - a02*a10)*id;
        invAS[6] =  c02*id;
        invAS[7] = -(a00*a21 - a01*a20)*id;
        invAS[8] =  (a00*a11 - a01*a10)*id;
        scaleS   = rsqrtf(fabsf(det));
    }
    __syncthreads();

    if (tid < NT) {
        int rg = r_base + tid; if (rg > NRPT-1) rg = NRPT-1;
        float r0 = rpts[rg*3+0], r1 = rpts[rg*3+1], r2 = rpts[rg*3+2];
        fracS[tid][0] = r0*invAS[0] + r1*invAS[3] + r2*invAS[6];
        fracS[tid][1] = r0*invAS[1] + r1*invAS[4] + r2*invAS[7];
        fracS[tid][2] = r0*invAS[2] + r1*invAS[5] + r2*invAS[8];
        #pragma unroll
        for (int kk = 0; kk < 4; ++kk)
            rkS[tid][kk] = r0*kgrid[kk*3+0] + r1*kgrid[kk*3+1] + r2*kgrid[kk*3+2];
    }
    __syncthreads();

    // T3[r][i3] = e^{2*pi*i * m3 * f2}, bf16-packed
    for (int e = tid; e < NT*20; e += TPB) {
        int r  = (e * 3277) >> 16;      // e/20
        int i3 = e - r*20;
        float m3 = (float)(i3 - (i3 >= 10 ? 20 : 0));
        float ang = m3 * fracS[r][2];
        float u = ang - floorf(ang);
        T3[r][i3] = cvt_pk(cos_rev(u), sin_rev(u));
    }

    f32x4 accRe[4][2], accIm[4][2];
    #pragma unroll
    for (int mi = 0; mi < 4; ++mi)
        #pragma unroll
        for (int ni = 0; ni < 2; ++ni) {
            accRe[mi][ni] = (f32x4){0.f,0.f,0.f,0.f};
            accIm[mi][ni] = (f32x4){0.f,0.f,0.f,0.f};
        }

    const int lane = tid & 63;
    const int wid  = tid >> 6;
    const int wm   = wid >> 2;      // 0..1  (M half)
    const int wn   = wid & 3;       // 0..3  (N quarter)
    const int frow = lane & 15;
    const int k0   = (lane >> 4) * 8;

    const int sa      = tid >> 2;   // A row 0..127
    const int seg     = tid & 3;    // k segment of 8
    const int rB      = tid >> 2;   // B r-row 0..127
    const int quarter = tid & 3;    // g segment of 8

    const float f0r = fracS[rB][0], f1r = fracS[rB][1];

    // ---- register prefetch of A (hides global latency under MFMA phase) ----
    float4 pvr0, pvr1, pvi0, pvi1;
    {
        int kg = k_begin + seg*8;
        const float* pr_ = &cgr[(size_t)sa*NG + kg];
        const float* pi_ = &cgi[(size_t)sa*NG + kg];
        pvr0 = *(const float4*)pr_;  pvr1 = *(const float4*)(pr_+4);
        pvi0 = *(const float4*)pi_;  pvi1 = *(const float4*)(pi_+4);
    }

    #pragma unroll 1
    for (int kb = k_begin; kb < k_end; kb += KK) {
        __syncthreads();   // WAR: previous tile's fragment reads complete

        // ---- stage A: cvt prefetched fp32 -> bf16, store ----
        {
            uint4 pr, pi;
            pr.x = cvt_pk(pvr0.x, pvr0.y); pr.y = cvt_pk(pvr0.z, pvr0.w);
            pr.z = cvt_pk(pvr1.x, pvr1.y); pr.w = cvt_pk(pvr1.z, pvr1.w);
            pi.x = cvt_pk(pvi0.x, pvi0.y); pi.y = cvt_pk(pvi0.z, pvi0.w);
            pi.z = cvt_pk(pvi1.x, pvi1.y); pi.w = cvt_pk(pvi1.z, pvi1.w);
            *(uint4*)&Ar[sa][seg*8] = pr;
            *(uint4*)&Ai[sa][seg*8] = pi;
        }
        // ---- stage B: phase = P12(i1,i2) * T3(i3) ----
        {
            int g0  = kb + quarter*8;
            int i12 = (g0 * 3277) >> 16;            // g0/20
            int i3_0 = g0 - i12*20;
            int i1a = (i12 * 3277) >> 16; int i2a = i12 - i1a*20;
            int i12b = i12 + 1;
            int i1b = (i12b * 3277) >> 16; int i2b = i12b - i1b*20;
            float m1a = (float)(i1a - (i1a >= 10 ? 20 : 0));
            float m2a = (float)(i2a - (i2a >= 10 ? 20 : 0));
            float m1b = (float)(i1b - (i1b >= 10 ? 20 : 0));
            float m2b = (float)(i2b - (i2b >= 10 ? 20 : 0));
            float aa = m1a*f0r + m2a*f1r; aa -= floorf(aa);
            float ab = m1b*f0r + m2b*f1r; ab -= floorf(ab);
            float ca = cos_rev(aa), sa2 = sin_rev(aa);
            float cb = cos_rev(ab), sb2 = sin_rev(ab);
            float bcv[8], bsv[8];
            #pragma unroll
            for (int j = 0; j < 8; ++j) {
                int t = i3_0 + j;
                bool wr = (t >= 20);
                int i3 = wr ? t - 20 : t;
                unsigned int pk = T3[rB][i3];
                float t3c = __uint_as_float(pk << 16);
                float t3s = __uint_as_float(pk & 0xFFFF0000u);
                float pc = wr ? cb : ca;
                float ps = wr ? sb2 : sa2;
                bcv[j] = pc*t3c - ps*t3s;
                bsv[j] = pc*t3s + ps*t3c;
            }
            uint4 wc, wsn;
            wc.x  = cvt_pk(bcv[0], bcv[1]); wc.y  = cvt_pk(bcv[2], bcv[3]);
            wc.z  = cvt_pk(bcv[4], bcv[5]); wc.w  = cvt_pk(bcv[6], bcv[7]);
            wsn.x = cvt_pk(bsv[0], bsv[1]); wsn.y = cvt_pk(bsv[2], bsv[3]);
            wsn.z = cvt_pk(bsv[4], bsv[5]); wsn.w = cvt_pk(bsv[6], bsv[7]);
            *(uint4*)&Bc[rB][quarter*8] = wc;
            *(uint4*)&Bs[rB][quarter*8] = wsn;
        }
        // ---- issue next tile's A loads (complete during MFMA phase) ----
        {
            int kb2 = kb + KK;
            int kg  = kb2 + seg*8;
            if (kb2 < k_end && kg < k_end) {
                const float* pr_ = &cgr[(size_t)sa*NG + kg];
                const float* pi_ = &cgi[(size_t)sa*NG + kg];
                pvr0 = *(const float4*)pr_;  pvr1 = *(const float4*)(pr_+4);
                pvi0 = *(const float4*)pi_;  pvi1 = *(const float4*)(pi_+4);
            } else {
                pvr0 = make_float4(0.f,0.f,0.f,0.f); pvr1 = pvr0;
                pvi0 = pvr0; pvi1 = pvr0;
            }
        }
        __syncthreads();   // RAW: staging visible

        // ---- fragments + MFMA: wave tile 64(m) x 32(n) ----
        s16x8 bcf[2], bsf[2];
        #pragma unroll
        for (int ni = 0; ni < 2; ++ni) {
            int col = wn*32 + ni*16 + frow;
            bcf[ni] = *(const s16x8*)&Bc[col][k0];
            bsf[ni] = *(const s16x8*)&Bs[col][k0];
        }
        #pragma unroll
        for (int mi = 0; mi < 4; ++mi) {
            int row = wm*64 + mi*16 + frow;
            s16x8 arf = *(const s16x8*)&Ar[row][k0];
            s16x8 aif = *(const s16x8*)&Ai[row][k0];
            s16x8 ainf = bneg(aif);
            #pragma unroll
            for (int ni = 0; ni < 2; ++ni) {
                accRe[mi][ni] = __builtin_amdgcn_mfma_f32_16x16x32_bf16(arf,  bcf[ni], accRe[mi][ni], 0, 0, 0);
                accRe[mi][ni] = __builtin_amdgcn_mfma_f32_16x16x32_bf16(ainf, bsf[ni], accRe[mi][ni], 0, 0, 0);
                accIm[mi][ni] = __builtin_amdgcn_mfma_f32_16x16x32_bf16(arf,  bsf[ni], accIm[mi][ni], 0, 0, 0);
                accIm[mi][ni] = __builtin_amdgcn_mfma_f32_16x16x32_bf16(aif,  bcf[ni], accIm[mi][ni], 0, 0, 0);
            }
        }
    }

    // ---- epilogue: rotate by exp(i k.r), scale, atomic-accumulate ----
    const bool write_imag = (out_size >= 2*NSKIN*NRPT);
    const float scale  = scaleS;
    const float inv2pi = 0.15915494309189535f;
    #pragma unroll
    for (int mi = 0; mi < 4; ++mi) {
        const int m0 = wm*64 + mi*16;
        const int kidx = (m0 >> 4) & 3;
        #pragma unroll
        for (int ni = 0; ni < 2; ++ni) {
            int col = wn*32 + ni*16 + frow;
            int rg = r_base + col;
            if (rg < NRPT) {
                float ang = rkS[col][kidx] * inv2pi;
                float u = ang - floorf(ang);
                float ck = cos_rev(u), sk = sin_rev(u);
                #pragma unroll
                for (int v = 0; v < 4; ++v) {
                    int sg = m0 + (lane >> 4)*4 + v;
                    float re = accRe[mi][ni][v];
                    float im = accIm[mi][ni][v];
                    float orr = (re*ck - im*sk) * scale;
                    size_t lin = (size_t)sg * NRPT + rg;
                    if (write_imag) {
                        float oi = (re*sk + im*ck) * scale;
                        size_t idx = lin * 2;
                        if (idx + 1 < (size_t)out_size) {
                            atomicAdd(&out[idx],   orr);
                            atomicAdd(&out[idx+1], oi);
                        }
                    } else {
                        if (lin < (size_t)out_size)
                            atomicAdd(&out[lin], orr);
                    }
                }
            }
        }
    }
}

extern "C" void kernel_launch(void* const* d_in, const int* in_sizes, int n_in,
                              void* d_out, int out_size, void* d_ws, size_t ws_size,
                              hipStream_t stream) {
    const float* Amat  = (const float*)d_in[0];
    const float* kgrid = (const float*)d_in[1];
    const float* cgr   = (const float*)d_in[2];
    const float* cgi   = (const float*)d_in[3];
    const float* rpts  = (const float*)d_in[4];
    float* out = (float*)d_out;

    hipMemsetAsync(d_out, 0, (size_t)out_size * sizeof(float), stream);

    dim3 grid(NRB * NKC);   // 64 rb x 8 kc = 512 blocks (2/CU)
    bloch_mfma3<<<grid, TPB, 0, stream>>>(Amat, kgrid, cgr, cgi, rpts, out, out_size);
}

// Round 5
// 103.326 us; speedup vs baseline: 1.8013x; 1.0619x over previous
//
#include <hip/hip_runtime.h>

typedef __attribute__((ext_vector_type(4))) float f32x4;
typedef __attribute__((ext_vector_type(8))) short s16x8;

#define NSKIN 128
#define NG    8000
#define NRPT  8000
#define MT    128
#define NT    128
#define KK    32
#define KCH   1000
#define NKC   8
#define NRB   64
#define TPB   512

__device__ __forceinline__ float sin_rev(float u){ float r; asm("v_sin_f32 %0, %1" : "=v"(r) : "v"(u)); return r; }
__device__ __forceinline__ float cos_rev(float u){ float r; asm("v_cos_f32 %0, %1" : "=v"(r) : "v"(u)); return r; }
__device__ __forceinline__ unsigned int cvt_pk(float lo, float hi){
    unsigned int r; asm("v_cvt_pk_bf16_f32 %0, %1, %2" : "=v"(r) : "v"(lo), "v"(hi)); return r;
}
__device__ __forceinline__ s16x8 bneg(s16x8 v){
    int4 u = *(int4*)&v;
    u.x ^= 0x80008000; u.y ^= 0x80008000; u.z ^= 0x80008000; u.w ^= 0x80008000;
    return *(s16x8*)&u;
}
// byte offset of 16B granule (row, kg) in a swizzled [128][32]-ushort tile.
// 64B rows; kg' = kg ^ ((row>>1)&3) makes both the b128 stage-writes
// (sa=tid>>2, seg=tid&3) and the b128 frag-reads (rows base+frow, kg=lane>>4)
// land exactly 8 lanes on each of the 8 16B bank-groups -> conflict-free.
__device__ __forceinline__ int swz(int row, int kg){
    return row*64 + ((kg ^ ((row>>1)&3))<<4);
}

__global__ __launch_bounds__(TPB, 4) void bloch_mfma4(
    const float* __restrict__ Amat, const float* __restrict__ kgrid,
    const float* __restrict__ cgr,  const float* __restrict__ cgi,
    const float* __restrict__ rpts, float* __restrict__ out, int out_size)
{
    __shared__ float fracS[NT][4];
    __shared__ float rkS[NT][4];
    __shared__ unsigned short Ar[MT*KK], Ai[MT*KK];
    __shared__ unsigned short Bc[NT*KK], Bs[NT*KK];
    __shared__ float invAS[9];
    __shared__ float scaleS;

    const int tid = threadIdx.x;
    const int bid = blockIdx.x;
    // kc = bid>>6: the 8 kc-partners of an output tile share bid%8 -> same XCD
    // -> epilogue atomic lines stay in one L2 (no cross-XCD ping-pong).
    const int kc  = bid >> 6;
    const int rb  = bid & 63;
    const int r_base  = rb * NT;
    const int k_begin = kc * KCH;
    const int k_end   = k_begin + KCH;

    if (tid == 0) {
        float a00=Amat[0],a01=Amat[1],a02=Amat[2];
        float a10=Amat[3],a11=Amat[4],a12=Amat[5];
        float a20=Amat[6],a21=Amat[7],a22=Amat[8];
        float c00 =  (a11*a22 - a12*a21);
        float c01 = -(a10*a22 - a12*a20);
        float c02 =  (a10*a21 - a11*a20);
        float det = a00*c00 + a01*c01 + a02*c02;
        float id  = 1.0f/det;
        invAS[0] =  c00*id;
        invAS[1] = -(a01*a22 - a02*a21)*id;
        invAS[2] =  (a01*a12 - a02*a11)*id;
        invAS[3] =  c01*id;
        invAS[4] =  (a00*a22 - a02*a20)*id;
        invAS[5] = -(a00*a12 - a02*a10)*id;
        invAS[6] =  c02*id;
        invAS[7] = -(a00*a21 - a01*a20)*id;
        invAS[8] =  (a00*a11 - a01*a10)*id;
        scaleS   = rsqrtf(fabsf(det));
    }
    __syncthreads();

    if (tid < NT) {
        int rg = r_base + tid; if (rg > NRPT-1) rg = NRPT-1;
        float r0 = rpts[rg*3+0], r1 = rpts[rg*3+1], r2 = rpts[rg*3+2];
        fracS[tid][0] = r0*invAS[0] + r1*invAS[3] + r2*invAS[6];
        fracS[tid][1] = r0*invAS[1] + r1*invAS[4] + r2*invAS[7];
        fracS[tid][2] = r0*invAS[2] + r1*invAS[5] + r2*invAS[8];
        #pragma unroll
        for (int kk = 0; kk < 4; ++kk)
            rkS[tid][kk] = r0*kgrid[kk*3+0] + r1*kgrid[kk*3+1] + r2*kgrid[kk*3+2];
    }
    __syncthreads();

    f32x4 accRe[4][2], accIm[4][2];
    #pragma unroll
    for (int mi = 0; mi < 4; ++mi)
        #pragma unroll
        for (int ni = 0; ni < 2; ++ni) {
            accRe[mi][ni] = (f32x4){0.f,0.f,0.f,0.f};
            accIm[mi][ni] = (f32x4){0.f,0.f,0.f,0.f};
        }

    const int lane = tid & 63;
    const int wid  = tid >> 6;
    const int wm   = wid >> 2;      // 0..1  (M half)
    const int wn   = wid & 3;       // 0..3  (N quarter)
    const int frow = lane & 15;
    const int kq   = lane >> 4;     // 16B granule index 0..3

    const int sa      = tid >> 2;   // stage row 0..127
    const int seg     = tid & 3;    // k granule 0..3
    const int rB      = sa;
    const int quarter = seg;

    const float f0r = fracS[rB][0], f1r = fracS[rB][1], f2r = fracS[rB][2];

    // per-thread recurrence constants: w1 = e^{2pi i f2}, w1wd = w1*e^{-2pi i 20 f2}
    float u1 = f2r - floorf(f2r);
    const float w1c = cos_rev(u1), w1s = sin_rev(u1);
    float yd = -20.0f * f2r; yd -= floorf(yd);
    const float wdc = cos_rev(yd), wds = sin_rev(yd);
    const float w1wdc = w1c*wdc - w1s*wds;
    const float w1wds = w1c*wds + w1s*wdc;

    // ---- register prefetch of A ----
    float4 pvr0, pvr1, pvi0, pvi1;
    {
        int kg = k_begin + seg*8;
        const float* pr_ = &cgr[(size_t)sa*NG + kg];
        const float* pi_ = &cgi[(size_t)sa*NG + kg];
        pvr0 = *(const float4*)pr_;  pvr1 = *(const float4*)(pr_+4);
        pvi0 = *(const float4*)pi_;  pvi1 = *(const float4*)(pi_+4);
    }

    #pragma unroll 1
    for (int kb = k_begin; kb < k_end; kb += KK) {
        __syncthreads();   // WAR: previous tile's fragment reads complete

        // ---- stage A: cvt prefetched fp32 -> bf16, swizzled store ----
        {
            uint4 pr, pi;
            pr.x = cvt_pk(pvr0.x, pvr0.y); pr.y = cvt_pk(pvr0.z, pvr0.w);
            pr.z = cvt_pk(pvr1.x, pvr1.y); pr.w = cvt_pk(pvr1.z, pvr1.w);
            pi.x = cvt_pk(pvi0.x, pvi0.y); pi.y = cvt_pk(pvi0.z, pvi0.w);
            pi.z = cvt_pk(pvi1.x, pvi1.y); pi.w = cvt_pk(pvi1.z, pvi1.w);
            *(uint4*)((char*)Ar + swz(sa, seg)) = pr;
            *(uint4*)((char*)Ai + swz(sa, seg)) = pi;
        }
        // ---- stage B: 8-phase run by complex recurrence (no table reads) ----
        {
            int g0   = kb + quarter*8;
            int i12  = (g0 * 3277) >> 16;            // g0/20 (exact for g0<16000)
            int i3_0 = g0 - i12*20;
            int i1a  = (i12 * 3277) >> 16; int i2a = i12 - i1a*20;
            int i12b = i12 + 1;
            int i1b  = (i12b * 3277) >> 16; int i2b = i12b - i1b*20;
            float m1a = (float)(i1a - (i1a >= 10 ? 20 : 0));
            float m2a = (float)(i2a - (i2a >= 10 ? 20 : 0));
            float m1b = (float)(i1b - (i1b >= 10 ? 20 : 0));
            float m2b = (float)(i2b - (i2b >= 10 ? 20 : 0));
            float m30 = (float)(i3_0 - (i3_0 >= 10 ? 20 : 0));
            // starting phase: P12(a) * e^{2pi i m3_0 f2} in ONE sincos
            float y0 = m1a*f0r + m2a*f1r + m30*f2r; y0 -= floorf(y0);
            float cc = cos_rev(y0), cs = sin_rev(y0);
            // i12-crossing multiplier: w1 * e^{2pi i ((m1b-m1a) f0 + (m2b-m2a) f1)}
            float rd = (m1b-m1a)*f0r + (m2b-m2a)*f1r; rd -= floorf(rd);
            float rc = cos_rev(rd), rs = sin_rev(rd);
            float wXc = w1c*rc - w1s*rs;
            float wXs = w1c*rs + w1s*rc;
            float bcv[8], bsv[8];
            bcv[0] = cc; bsv[0] = cs;
            #pragma unroll
            for (int j = 1; j < 8; ++j) {
                bool cB = (i3_0 == 20 - j);   // i12 boundary at this step
                bool cD = (i3_0 == 10 - j);   // m3 decade jump at this step
                float mc = cB ? wXc : (cD ? w1wdc : w1c);
                float ms = cB ? wXs : (cD ? w1wds : w1s);
                float nc = cc*mc - cs*ms;
                float ns = cc*ms + cs*mc;
                cc = nc; cs = ns;
                bcv[j] = cc; bsv[j] = cs;
            }
            uint4 wc, wsn;
            wc.x  = cvt_pk(bcv[0], bcv[1]); wc.y  = cvt_pk(bcv[2], bcv[3]);
            wc.z  = cvt_pk(bcv[4], bcv[5]); wc.w  = cvt_pk(bcv[6], bcv[7]);
            wsn.x = cvt_pk(bsv[0], bsv[1]); wsn.y = cvt_pk(bsv[2], bsv[3]);
            wsn.z = cvt_pk(bsv[4], bsv[5]); wsn.w = cvt_pk(bsv[6], bsv[7]);
            *(uint4*)((char*)Bc + swz(rB, quarter)) = wc;
            *(uint4*)((char*)Bs + swz(rB, quarter)) = wsn;
        }
        // ---- issue next tile's A loads (complete during MFMA phase) ----
        {
            int kb2 = kb + KK;
            int kg  = kb2 + seg*8;
            if (kb2 < k_end && kg < k_end) {
                const float* pr_ = &cgr[(size_t)sa*NG + kg];
                const float* pi_ = &cgi[(size_t)sa*NG + kg];
                pvr0 = *(const float4*)pr_;  pvr1 = *(const float4*)(pr_+4);
                pvi0 = *(const float4*)pi_;  pvi1 = *(const float4*)(pi_+4);
            } else {
                pvr0 = make_float4(0.f,0.f,0.f,0.f); pvr1 = pvr0;
                pvi0 = pvr0; pvi1 = pvr0;
            }
        }
        __syncthreads();   // RAW: staging visible

        // ---- fragments + MFMA: wave tile 64(m) x 32(n) ----
        s16x8 bcf[2], bsf[2], bsnf[2];
        #pragma unroll
        for (int ni = 0; ni < 2; ++ni) {
            int col = wn*32 + ni*16 + frow;
            bcf[ni]  = *(const s16x8*)((const char*)Bc + swz(col, kq));
            bsf[ni]  = *(const s16x8*)((const char*)Bs + swz(col, kq));
            bsnf[ni] = bneg(bsf[ni]);
        }
        #pragma unroll
        for (int mi = 0; mi < 4; ++mi) {
            int row = wm*64 + mi*16 + frow;
            s16x8 arf = *(const s16x8*)((const char*)Ar + swz(row, kq));
            s16x8 aif = *(const s16x8*)((const char*)Ai + swz(row, kq));
            #pragma unroll
            for (int ni = 0; ni < 2; ++ni) {
                // Re += Ar*c + Ai*(-s) ; Im += Ar*s + Ai*c
                accRe[mi][ni] = __builtin_amdgcn_mfma_f32_16x16x32_bf16(arf, bcf[ni],  accRe[mi][ni], 0, 0, 0);
                accRe[mi][ni] = __builtin_amdgcn_mfma_f32_16x16x32_bf16(aif, bsnf[ni], accRe[mi][ni], 0, 0, 0);
                accIm[mi][ni] = __builtin_amdgcn_mfma_f32_16x16x32_bf16(arf, bsf[ni],  accIm[mi][ni], 0, 0, 0);
                accIm[mi][ni] = __builtin_amdgcn_mfma_f32_16x16x32_bf16(aif, bcf[ni],  accIm[mi][ni], 0, 0, 0);
            }
        }
    }

    // ---- epilogue: rotate by exp(i k.r), scale, atomic-accumulate ----
    const bool write_imag = (out_size >= 2*NSKIN*NRPT);
    const float scale  = scaleS;
    const float inv2pi = 0.15915494309189535f;
    #pragma unroll
    for (int mi = 0; mi < 4; ++mi) {
        const int m0 = wm*64 + mi*16;
        const int kidx = (m0 >> 4) & 3;
        #pragma unroll
        for (int ni = 0; ni < 2; ++ni) {
            int col = wn*32 + ni*16 + frow;
            int rg = r_base + col;
            if (rg < NRPT) {
                float ang = rkS[col][kidx] * inv2pi;
                float u = ang - floorf(ang);
                float ck = cos_rev(u), sk = sin_rev(u);
                #pragma unroll
                for (int v = 0; v < 4; ++v) {
                    int sg = m0 + (lane >> 4)*4 + v;
                    float re = accRe[mi][ni][v];
                    float im = accIm[mi][ni][v];
                    float orr = (re*ck - im*sk) * scale;
                    size_t lin = (size_t)sg * NRPT + rg;
                    if (write_imag) {
                        float oi = (re*sk + im*ck) * scale;
                        size_t idx = lin * 2;
                        if (idx + 1 < (size_t)out_size) {
                            atomicAdd(&out[idx],   orr);
                            atomicAdd(&out[idx+1], oi);
                        }
                    } else {
                        if (lin < (size_t)out_size)
                            atomicAdd(&out[lin], orr);
                    }
                }
            }
        }
    }
}

extern "C" void kernel_launch(void* const* d_in, const int* in_sizes, int n_in,
                              void* d_out, int out_size, void* d_ws, size_t ws_size,
                              hipStream_t stream) {
    const float* Amat  = (const float*)d_in[0];
    const float* kgrid = (const float*)d_in[1];
    const float* cgr   = (const float*)d_in[2];
    const float* cgi   = (const float*)d_in[3];
    const float* rpts  = (const float*)d_in[4];
    float* out = (float*)d_out;

    hipMemsetAsync(d_out, 0, (size_t)out_size * sizeof(float), stream);

    dim3 grid(NRB * NKC);   // 64 rb x 8 kc = 512 blocks (2/CU)
    bloch_mfma4<<<grid, TPB, 0, stream>>>(Amat, kgrid, cgr, cgi, rpts, out, out_size);
}